// Round 3
// baseline (547.195 us; speedup 1.0000x reference)
//
#include <hip/hip_runtime.h>
#include <hip/hip_bf16.h>
#include <stdint.h>

typedef __bf16 bf16x8 __attribute__((ext_vector_type(8)));
typedef float  f32x4  __attribute__((ext_vector_type(4)));

#define D_MODEL 1024
#define NUM_HEADS 16
#define D_K 64
#define BATCH 2
#define SEQ 2048
#define M_TOTAL (BATCH * SEQ)   // 4096

static __device__ __forceinline__ bf16x8 load8(const __bf16* p) {
    return *reinterpret_cast<const bf16x8*>(p);
}

// Adaptive 8-element fragment load: base is either fp32 or bf16 data,
// elem_off must be a multiple of 8 (so fp32 path is 32B-aligned).
static __device__ __forceinline__ bf16x8 load_any8(const void* base, size_t elem_off, int fp32mode) {
    if (fp32mode) {
        const float* p = (const float*)base + elem_off;
        f32x4 a = *reinterpret_cast<const f32x4*>(p);
        f32x4 c = *reinterpret_cast<const f32x4*>(p + 4);
        bf16x8 r;
#pragma unroll
        for (int i = 0; i < 4; i++) { r[i] = (__bf16)a[i]; r[4 + i] = (__bf16)c[i]; }
        return r;
    }
    return *reinterpret_cast<const bf16x8*>((const __bf16*)base + elem_off);
}

#define MFMA16(a, b, c) __builtin_amdgcn_mfma_f32_16x16x32_bf16((a), (b), (c), 0, 0, 0)

// ---------------------------------------------------------------------------
// Input dtype detection. If x is fp32, the LOW 16 bits of each 32-bit word
// are low mantissa bits (uniform random) -> interpreting them as bf16 gives
// wild exponents with p~0.8 per word. If x is bf16, the low half-word is a
// genuine N(0,1) sample (exp field in [90,135] for |v| in [2^-37, 2^64]).
// One wild word among 256 samples => fp32.
// ---------------------------------------------------------------------------
__global__ void detect_kernel(const uint32_t* __restrict__ x, int* __restrict__ flag) {
    __shared__ int s_wild;
    if (threadIdx.x == 0) s_wild = 0;
    __syncthreads();
    const uint32_t w   = x[threadIdx.x];
    const uint32_t lo  = w & 0xffffu;
    const uint32_t exf = (lo >> 7) & 0xffu;
    const bool sane = (lo == 0u) || (lo == 0x8000u) || (exf >= 90u && exf <= 135u);
    if (!sane) atomicExch(&s_wild, 1);
    __syncthreads();
    if (threadIdx.x == 0) *flag = s_wild;   // 1 = fp32 inputs, 0 = bf16 inputs
}

// ---------------------------------------------------------------------------
// QKV projection: Y = X * W^T, output (canonical bf16) remapped to [b,h,s,dk]
// block = 256 (4 waves, 2x2), wave tile 64x64, block tile 128x128
// grid = (M/128, N/128, 3)  -> z selects Wq/Wk/Wv
// ---------------------------------------------------------------------------
__global__ __launch_bounds__(256) void qkv_kernel(
    const void* __restrict__ X,
    const void* __restrict__ Wq,
    const void* __restrict__ Wk,
    const void* __restrict__ Wv,
    const int*  __restrict__ flag,
    __bf16* __restrict__ Qb,
    __bf16* __restrict__ Kb,
    __bf16* __restrict__ Vb)
{
    const int mode = *flag;
    const int lane = threadIdx.x & 63;
    const int wid  = threadIdx.x >> 6;
    const int m    = lane & 15;
    const int quad = lane >> 4;
    const int wrow = wid >> 1, wcol = wid & 1;
    const int row0 = blockIdx.x * 128 + wrow * 64;
    const int col0 = blockIdx.y * 128 + wcol * 64;

    const void* W  = (blockIdx.z == 0) ? Wq : (blockIdx.z == 1) ? Wk : Wv;
    __bf16* Out    = (blockIdx.z == 0) ? Qb : (blockIdx.z == 1) ? Kb : Vb;

    f32x4 acc[4][4];
#pragma unroll
    for (int i = 0; i < 4; i++)
#pragma unroll
        for (int j = 0; j < 4; j++)
            acc[i][j] = (f32x4){0.f, 0.f, 0.f, 0.f};

    const size_t aoff = (size_t)(row0 + m) * D_MODEL + quad * 8;
    const size_t boff = (size_t)(col0 + m) * D_MODEL + quad * 8;

    for (int k0 = 0; k0 < D_MODEL; k0 += 32) {
        bf16x8 a[4], b[4];
#pragma unroll
        for (int i = 0; i < 4; i++) a[i] = load_any8(X, aoff + (size_t)i * 16 * D_MODEL + k0, mode);
#pragma unroll
        for (int j = 0; j < 4; j++) b[j] = load_any8(W, boff + (size_t)j * 16 * D_MODEL + k0, mode);
#pragma unroll
        for (int i = 0; i < 4; i++)
#pragma unroll
            for (int j = 0; j < 4; j++)
                acc[i][j] = MFMA16(a[i], b[j], acc[i][j]);
    }

    // epilogue: C row = row0+i*16+quad*4+r, col = col0+j*16+m; remap -> [b,h,s,dk]
#pragma unroll
    for (int i = 0; i < 4; i++) {
#pragma unroll
        for (int r = 0; r < 4; r++) {
            const int R    = row0 + i * 16 + quad * 4 + r;
            const int bIdx = R >> 11;          // /SEQ
            const int s    = R & (SEQ - 1);
#pragma unroll
            for (int j = 0; j < 4; j++) {
                const int E  = col0 + j * 16 + m;
                const int h  = E >> 6;         // /D_K
                const int dk = E & (D_K - 1);
                const size_t o = (((size_t)(bIdx * NUM_HEADS + h)) * SEQ + s) * D_K + dk;
                Out[o] = (__bf16)acc[i][j][r];
            }
        }
    }
}

// ---------------------------------------------------------------------------
// Flash attention, causal. grid = (SEQ/64, BATCH*NUM_HEADS), block = 256.
// All-bf16 (reads canonical ws buffers). Unchanged from round 2.
// ---------------------------------------------------------------------------
__global__ __launch_bounds__(256) void attn_kernel(
    const __bf16* __restrict__ Qb,
    const __bf16* __restrict__ Kb,
    const __bf16* __restrict__ Vb,
    __bf16* __restrict__ Cc)
{
    const int lane = threadIdx.x & 63;
    const int wid  = threadIdx.x >> 6;
    const int m    = lane & 15;
    const int quad = lane >> 4;
    const int bh   = blockIdx.y;
    const int b    = bh >> 4;
    const int h    = bh & (NUM_HEADS - 1);
    const size_t base = (size_t)bh * SEQ * D_K;
    const __bf16* Qp = Qb + base;
    const __bf16* Kp = Kb + base;
    const __bf16* Vp = Vb + base;

    const int q0 = blockIdx.x * 64 + wid * 16;   // this wave's first q row

    __shared__ alignas(16) __bf16 Ks[32][72];
    __shared__ alignas(16) __bf16 Vt[64][40];
    __shared__ alignas(16) __bf16 Ps[4][16][40];

    const bf16x8 qf0 = load8(Qp + (size_t)(q0 + m) * D_K + quad * 8);
    const bf16x8 qf1 = load8(Qp + (size_t)(q0 + m) * D_K + 32 + quad * 8);

    f32x4 oacc[4];
#pragma unroll
    for (int c = 0; c < 4; c++) oacc[c] = (f32x4){0.f, 0.f, 0.f, 0.f};
    float mrow[4] = {-1e30f, -1e30f, -1e30f, -1e30f};
    float lrow[4] = {0.f, 0.f, 0.f, 0.f};

    const int kend = blockIdx.x * 64 + 64;   // exclusive; causal block bound
    for (int k0 = 0; k0 < kend; k0 += 32) {
        // ---- cooperative stage: K[32][64] and V^T[64][32] ----
        {
            const int key = threadIdx.x >> 3;
            const int d   = (threadIdx.x & 7) * 8;
            bf16x8 kv = load8(Kp + (size_t)(k0 + key) * D_K + d);
            *reinterpret_cast<bf16x8*>(&Ks[key][d]) = kv;
            bf16x8 vv = load8(Vp + (size_t)(k0 + key) * D_K + d);
#pragma unroll
            for (int e = 0; e < 8; e++) Vt[d + e][key] = vv[e];
        }
        __syncthreads();

        // ---- S = Q K^T (two 16-key halves), scale, causal mask ----
        float p[2][4];
#pragma unroll
        for (int half = 0; half < 2; half++) {
            bf16x8 kf0 = load8(&Ks[half * 16 + m][quad * 8]);
            bf16x8 kf1 = load8(&Ks[half * 16 + m][32 + quad * 8]);
            f32x4 s = (f32x4){0.f, 0.f, 0.f, 0.f};
            s = MFMA16(qf0, kf0, s);
            s = MFMA16(qf1, kf1, s);
#pragma unroll
            for (int r = 0; r < 4; r++) {
                const int q   = q0 + quad * 4 + r;
                const int key = k0 + half * 16 + m;
                const float v = s[r] * 0.125f;           // 1/sqrt(64)
                p[half][r] = (key <= q) ? v : -1e30f;
            }
        }

        // ---- V fragments for this tile (must precede sync2) ----
        bf16x8 vf[4];
#pragma unroll
        for (int c = 0; c < 4; c++) vf[c] = load8(&Vt[c * 16 + m][quad * 8]);

        // ---- online softmax per row (reduce over 16 lanes of the quad) ----
        float alpha[4];
#pragma unroll
        for (int r = 0; r < 4; r++) {
            float lmax = fmaxf(p[0][r], p[1][r]);
#pragma unroll
            for (int off = 1; off < 16; off <<= 1)
                lmax = fmaxf(lmax, __shfl_xor(lmax, off, 16));
            const float mnew = fmaxf(mrow[r], lmax);
            alpha[r] = __expf(fminf(mrow[r] - mnew, 0.f));
            const float e0 = __expf(fminf(p[0][r] - mnew, 0.f));
            const float e1 = __expf(fminf(p[1][r] - mnew, 0.f));
            float lsum = e0 + e1;
#pragma unroll
            for (int off = 1; off < 16; off <<= 1)
                lsum += __shfl_xor(lsum, off, 16);
            lrow[r] = lrow[r] * alpha[r] + lsum;
            mrow[r] = mnew;
            Ps[wid][quad * 4 + r][m]      = (__bf16)e0;
            Ps[wid][quad * 4 + r][16 + m] = (__bf16)e1;
        }
#pragma unroll
        for (int c = 0; c < 4; c++) {
#pragma unroll
            for (int r = 0; r < 4; r++) oacc[c][r] *= alpha[r];
        }

        __syncthreads();   // order Ps write->read; protect Ks/Vt for restage

        // ---- P·V: P (A-layout from LDS), V^T frags (B-layout) ----
        bf16x8 pf = load8(&Ps[wid][m][quad * 8]);
#pragma unroll
        for (int c = 0; c < 4; c++)
            oacc[c] = MFMA16(pf, vf[c], oacc[c]);
    }

    // ---- epilogue: O /= l, store concat [b, s, h*64+d] ----
#pragma unroll
    for (int r = 0; r < 4; r++) {
        const int s = q0 + quad * 4 + r;
        const float inv = 1.f / lrow[r];
#pragma unroll
        for (int c = 0; c < 4; c++) {
            const size_t o = ((size_t)(b * SEQ + s)) * D_MODEL + h * D_K + c * 16 + m;
            Cc[o] = (__bf16)(oacc[c][r] * inv);
        }
    }
}

// ---------------------------------------------------------------------------
// Output projection: Out = Cc * Wo^T + bo.  A from bf16 ws; B/bias/store
// adaptive to the detected dtype.  grid = (M/128, N/128), block = 256.
// ---------------------------------------------------------------------------
__global__ __launch_bounds__(256) void oproj_kernel(
    const __bf16* __restrict__ Cc,
    const void*   __restrict__ Wo,
    const void*   __restrict__ bo,
    const int*    __restrict__ flag,
    void* __restrict__ OutV)
{
    const int mode = *flag;
    const int lane = threadIdx.x & 63;
    const int wid  = threadIdx.x >> 6;
    const int m    = lane & 15;
    const int quad = lane >> 4;
    const int wrow = wid >> 1, wcol = wid & 1;
    const int row0 = blockIdx.x * 128 + wrow * 64;
    const int col0 = blockIdx.y * 128 + wcol * 64;

    f32x4 acc[4][4];
#pragma unroll
    for (int i = 0; i < 4; i++)
#pragma unroll
        for (int j = 0; j < 4; j++)
            acc[i][j] = (f32x4){0.f, 0.f, 0.f, 0.f};

    const __bf16* Arow = Cc + (size_t)(row0 + m) * D_MODEL + quad * 8;
    const size_t  boff = (size_t)(col0 + m) * D_MODEL + quad * 8;

    for (int k0 = 0; k0 < D_MODEL; k0 += 32) {
        bf16x8 a[4], b[4];
#pragma unroll
        for (int i = 0; i < 4; i++) a[i] = load8(Arow + (size_t)i * 16 * D_MODEL + k0);
#pragma unroll
        for (int j = 0; j < 4; j++) b[j] = load_any8(Wo, boff + (size_t)j * 16 * D_MODEL + k0, mode);
#pragma unroll
        for (int i = 0; i < 4; i++)
#pragma unroll
            for (int j = 0; j < 4; j++)
                acc[i][j] = MFMA16(a[i], b[j], acc[i][j]);
    }

#pragma unroll
    for (int i = 0; i < 4; i++) {
#pragma unroll
        for (int r = 0; r < 4; r++) {
            const int R = row0 + i * 16 + quad * 4 + r;
#pragma unroll
            for (int j = 0; j < 4; j++) {
                const int E = col0 + j * 16 + m;
                const float bias = mode ? ((const float*)bo)[E]
                                        : (float)((const __bf16*)bo)[E];
                const float v = acc[i][j][r] + bias;
                const size_t o = (size_t)R * D_MODEL + E;
                if (mode) ((float*)OutV)[o]  = v;
                else      ((__bf16*)OutV)[o] = (__bf16)v;
            }
        }
    }
}

// ---------------------------------------------------------------------------
extern "C" void kernel_launch(void* const* d_in, const int* in_sizes, int n_in,
                              void* d_out, int out_size, void* d_ws, size_t ws_size,
                              hipStream_t stream) {
    const void* x  = d_in[0];
    const void* Wq = d_in[1];
    const void* Wk = d_in[2];
    const void* Wv = d_in[3];
    const void* Wo = d_in[4];
    const void* bo = d_in[5];
    // d_in[6] = causal mask — recomputed from indices, not read.

    // ws layout: [flag int, 256B pad] [Qb 8MB] [Kb 8MB] [Vb 8MB] [Cc 8MB]
    int* flag = (int*)d_ws;
    const size_t elems = (size_t)M_TOTAL * D_MODEL;   // 4096*1024
    __bf16* Qb = (__bf16*)((char*)d_ws + 256);
    __bf16* Kb = Qb + elems;
    __bf16* Vb = Kb + elems;
    __bf16* Cc = Vb + elems;

    // 0) detect input dtype (fp32 vs bf16) from x's bit patterns
    detect_kernel<<<1, 256, 0, stream>>>((const uint32_t*)x, flag);

    // 1) QKV projections (fused in one launch via grid.z) -> canonical bf16
    qkv_kernel<<<dim3(M_TOTAL / 128, D_MODEL / 128, 3), 256, 0, stream>>>(
        x, Wq, Wk, Wv, flag, Qb, Kb, Vb);

    // 2) causal flash attention -> concat layout (bf16)
    attn_kernel<<<dim3(SEQ / 64, BATCH * NUM_HEADS), 256, 0, stream>>>(
        Qb, Kb, Vb, Cc);

    // 3) output projection + bias, dtype-adaptive store
    oproj_kernel<<<dim3(M_TOTAL / 128, D_MODEL / 128), 256, 0, stream>>>(
        Cc, Wo, bo, flag, d_out);
}

// Round 4
// 253.984 us; speedup vs baseline: 2.1545x; 2.1545x over previous
//
#include <hip/hip_runtime.h>
#include <hip/hip_bf16.h>
#include <stdint.h>

typedef __bf16 bf16x8 __attribute__((ext_vector_type(8)));
typedef float  f32x4  __attribute__((ext_vector_type(4)));

#define D_MODEL 1024
#define NUM_HEADS 16
#define D_K 64
#define BATCH 2
#define SEQ 2048
#define M_TOTAL (BATCH * SEQ)   // 4096

static __device__ __forceinline__ bf16x8 load8(const __bf16* p) {
    return *reinterpret_cast<const bf16x8*>(p);
}

#define MFMA16(a, b, c) __builtin_amdgcn_mfma_f32_16x16x32_bf16((a), (b), (c), 0, 0, 0)

// Async global->LDS, 16B per lane. LDS dest = wave-uniform base + lane*16.
static __device__ __forceinline__ void gload16(const void* g, const void* lds) {
    __builtin_amdgcn_global_load_lds(
        (const __attribute__((address_space(1))) uint32_t*)g,
        (__attribute__((address_space(3))) uint32_t*)lds,
        16, 0, 0);
}

// ---------------------------------------------------------------------------
// fp32 -> bf16 conversion for x (4M elems). 8 elems/thread.
// ---------------------------------------------------------------------------
__global__ __launch_bounds__(256) void convert_kernel(
    const float* __restrict__ X, __bf16* __restrict__ Xb)
{
    const int idx = blockIdx.x * 256 + threadIdx.x;   // < 524288
    const f32x4 a = *reinterpret_cast<const f32x4*>(X + (size_t)idx * 8);
    const f32x4 b = *reinterpret_cast<const f32x4*>(X + (size_t)idx * 8 + 4);
    bf16x8 r;
#pragma unroll
    for (int e = 0; e < 4; e++) { r[e] = (__bf16)a[e]; r[4 + e] = (__bf16)b[e]; }
    *reinterpret_cast<bf16x8*>(Xb + (size_t)idx * 8) = r;
}

// ---------------------------------------------------------------------------
// QKV projection, m97 structure: 128x128 tile, BK=32, global_load_lds(16B).
// A = xb (bf16, standard m97 layout). B = W (fp32) staged with XOR-swizzled
// 16B-chunk mapping: row stride 128B == 0 mod 32 banks, so unswizzled reads
// would be 16-way conflicted; k4 ^= (row&7) spreads lanes m..m+15 across 8
// bank-groups (2-way = free). Epilogue remaps to [bh][s][dk] (Q,K) and
// [bh][dk][s] (V pre-transposed for attention's B-fragment staging).
// grid = (4096/128, 3072/128) = (32, 24), block = 256.
// ---------------------------------------------------------------------------
__global__ __launch_bounds__(256) void qkv_kernel(
    const __bf16* __restrict__ Xb,
    const float* __restrict__ Wq,
    const float* __restrict__ Wk,
    const float* __restrict__ Wv,
    __bf16* __restrict__ Qb,
    __bf16* __restrict__ Kb,
    __bf16* __restrict__ Vtg)
{
    __shared__ __bf16 As[128 * 32];   // 8 KB, [row][k] row-major, no pad
    __shared__ float  Bsf[128 * 32];  // 16 KB, [col][k4-swizzled]

    const int lane = threadIdx.x & 63;
    const int wid  = threadIdx.x >> 6;
    const int m    = lane & 15;
    const int quad = lane >> 4;
    const int wrow = wid >> 1, wcol = wid & 1;
    const int row0 = blockIdx.x * 128;
    const int col0 = blockIdx.y * 128;       // 0..2944 across Wq|Wk|Wv
    const int wsel = col0 >> 10;
    const int lcol0 = col0 & 1023;

    const float* W = (wsel == 0) ? Wq : (wsel == 1) ? Wk : Wv;

    f32x4 acc[4][4];
#pragma unroll
    for (int i = 0; i < 4; i++)
#pragma unroll
        for (int j = 0; j < 4; j++) acc[i][j] = (f32x4){0.f, 0.f, 0.f, 0.f};

    for (int k0 = 0; k0 < D_MODEL; k0 += 32) {
        // ---- stage A (bf16, 512 x 16B chunks) ----
#pragma unroll
        for (int i = 0; i < 2; i++) {
            const int slot = wid * 128 + i * 64 + lane;          // LDS chunk
            const int arow = slot >> 2, k8 = slot & 3;
            gload16(Xb + (size_t)(row0 + arow) * D_MODEL + k0 + k8 * 8,
                    (const char*)As + (size_t)(wid * 128 + i * 64) * 16);
        }
        // ---- stage B (fp32, 1024 x 16B chunks, XOR swizzle) ----
#pragma unroll
        for (int i = 0; i < 4; i++) {
            const int slot = wid * 256 + i * 64 + lane;
            const int brow = slot >> 3, k4s = slot & 7;
            const int k4g = k4s ^ (brow & 7);
            gload16(W + (size_t)(lcol0 + brow) * D_MODEL + k0 + k4g * 4,
                    (const char*)Bsf + (size_t)(wid * 256 + i * 64) * 16);
        }
        __syncthreads();   // drains vmcnt -> staging visible

        bf16x8 a[4], b[4];
#pragma unroll
        for (int i = 0; i < 4; i++)
            a[i] = load8(&As[(wrow * 64 + i * 16 + m) * 32 + quad * 8]);
#pragma unroll
        for (int j = 0; j < 4; j++) {
            const int brow = wcol * 64 + j * 16 + m;
            const int sw = brow & 7;
            const f32x4 lo = *reinterpret_cast<const f32x4*>(
                &Bsf[brow * 32 + (((quad * 2 + 0) ^ sw) * 4)]);
            const f32x4 hi = *reinterpret_cast<const f32x4*>(
                &Bsf[brow * 32 + (((quad * 2 + 1) ^ sw) * 4)]);
#pragma unroll
            for (int e = 0; e < 4; e++) { b[j][e] = (__bf16)lo[e]; b[j][4 + e] = (__bf16)hi[e]; }
        }
#pragma unroll
        for (int i = 0; i < 4; i++)
#pragma unroll
            for (int j = 0; j < 4; j++)
                acc[i][j] = MFMA16(a[i], b[j], acc[i][j]);
        __syncthreads();   // all LDS reads done before next stage
    }

    // ---- epilogue: remap to per-head layouts ----
#pragma unroll
    for (int i = 0; i < 4; i++) {
#pragma unroll
        for (int r = 0; r < 4; r++) {
            const int R  = row0 + wrow * 64 + i * 16 + quad * 4 + r;
            const int bb = R >> 11;
            const int s  = R & (SEQ - 1);
#pragma unroll
            for (int j = 0; j < 4; j++) {
                const int e  = lcol0 + wcol * 64 + j * 16 + m;
                const int h  = e >> 6;
                const int dk = e & (D_K - 1);
                const int bh = bb * NUM_HEADS + h;
                const __bf16 v = (__bf16)acc[i][j][r];
                if (wsel == 2)
                    Vtg[((size_t)bh * D_K + dk) * SEQ + s] = v;            // V^T
                else if (wsel == 1)
                    Kb[((size_t)bh * SEQ + s) * D_K + dk] = v;
                else
                    Qb[((size_t)bh * SEQ + s) * D_K + dk] = v;
            }
        }
    }
}

// ---------------------------------------------------------------------------
// Flash attention, causal, Bc=64. grid = (32 bh, 32 qy), block = 256 (4 waves).
// qy -> qx via a balanced permutation: co-resident blocks (stride-256 sets,
// fixed lo = qy&7, hi = qy>>3) get qx in {lo, 31-lo, 8+lo, 23-lo} whose work
// (qx+1 tiles) sums to a constant 66 -> uniform per-CU load (fixes the
// round-3 19% occupancy: work prop. to qx correlated with CU assignment).
// K staged row-major, V staged from the pre-transposed Vtg -- all vector LDS
// writes (kills the 2e7 scalar-transpose bank conflicts).
// ---------------------------------------------------------------------------
__global__ __launch_bounds__(256) void attn_kernel(
    const __bf16* __restrict__ Qb,
    const __bf16* __restrict__ Kb,
    const __bf16* __restrict__ Vtg,
    __bf16* __restrict__ Cc)
{
    __shared__ alignas(16) __bf16 Ks[64][72];      // [key][d], +8 pad
    __shared__ alignas(16) __bf16 Vt[64][72];      // [d][key], +8 pad
    __shared__ alignas(16) __bf16 Ps[4][16][72];   // per-wave P, +8 pad

    const int lane = threadIdx.x & 63;
    const int wid  = threadIdx.x >> 6;
    const int m    = lane & 15;
    const int quad = lane >> 4;
    const int bh   = blockIdx.x;
    const int b    = bh >> 4;
    const int h    = bh & (NUM_HEADS - 1);

    const int lo = blockIdx.y & 7, hi = blockIdx.y >> 3;
    const int qx = (hi == 0) ? lo : (hi == 1) ? 31 - lo : (hi == 2) ? 8 + lo : 23 - lo;

    const __bf16* Qp = Qb  + (size_t)bh * SEQ * D_K;
    const __bf16* Kp = Kb  + (size_t)bh * SEQ * D_K;
    const __bf16* Vp = Vtg + (size_t)bh * D_K * SEQ;

    const int q0 = qx * 64 + wid * 16;   // this wave's first q row

    const bf16x8 qf0 = load8(Qp + (size_t)(q0 + m) * D_K + quad * 8);
    const bf16x8 qf1 = load8(Qp + (size_t)(q0 + m) * D_K + 32 + quad * 8);

    f32x4 oacc[4];
#pragma unroll
    for (int c = 0; c < 4; c++) oacc[c] = (f32x4){0.f, 0.f, 0.f, 0.f};
    float mrow[4] = {-1e30f, -1e30f, -1e30f, -1e30f};
    float lrow[4] = {0.f, 0.f, 0.f, 0.f};

    const int ntiles = qx + 1;
    for (int t = 0; t < ntiles; t++) {
        const int k0 = t * 64;
        // ---- cooperative vector staging: K[64][64], V^T[64][64] ----
        {
            const int a = threadIdx.x >> 2;          // 0..63
            const int c = (threadIdx.x & 3) * 16;    // 0,16,32,48
            *reinterpret_cast<bf16x8*>(&Ks[a][c])     = load8(Kp + (size_t)(k0 + a) * D_K + c);
            *reinterpret_cast<bf16x8*>(&Ks[a][c + 8]) = load8(Kp + (size_t)(k0 + a) * D_K + c + 8);
            *reinterpret_cast<bf16x8*>(&Vt[a][c])     = load8(Vp + (size_t)a * SEQ + k0 + c);
            *reinterpret_cast<bf16x8*>(&Vt[a][c + 8]) = load8(Vp + (size_t)a * SEQ + k0 + c + 8);
        }
        __syncthreads();

        // ---- S = Q K^T over 4 key-blocks of 16, scale + causal mask ----
        float p[4][4];
#pragma unroll
        for (int kb = 0; kb < 4; kb++) {
            const bf16x8 kfA = load8(&Ks[kb * 16 + m][quad * 8]);
            const bf16x8 kfB = load8(&Ks[kb * 16 + m][32 + quad * 8]);
            f32x4 s = (f32x4){0.f, 0.f, 0.f, 0.f};
            s = MFMA16(qf0, kfA, s);
            s = MFMA16(qf1, kfB, s);
#pragma unroll
            for (int r = 0; r < 4; r++) {
                const int q   = q0 + quad * 4 + r;
                const int key = k0 + kb * 16 + m;
                p[kb][r] = (key <= q) ? s[r] * 0.125f : -1e30f;
            }
        }

        // ---- V fragments (must precede sync2: Vt restaged next tile) ----
        bf16x8 vfA[4], vfB[4];
#pragma unroll
        for (int c = 0; c < 4; c++) {
            vfA[c] = load8(&Vt[c * 16 + m][quad * 8]);
            vfB[c] = load8(&Vt[c * 16 + m][32 + quad * 8]);
        }

        // ---- online softmax (16-lane shuffle reduce per row) ----
        float alpha[4];
#pragma unroll
        for (int r = 0; r < 4; r++) {
            float lmax = fmaxf(fmaxf(p[0][r], p[1][r]), fmaxf(p[2][r], p[3][r]));
#pragma unroll
            for (int off = 1; off < 16; off <<= 1)
                lmax = fmaxf(lmax, __shfl_xor(lmax, off, 16));
            const float mnew = fmaxf(mrow[r], lmax);
            alpha[r] = __expf(fminf(mrow[r] - mnew, 0.f));
            const float e0 = __expf(fminf(p[0][r] - mnew, 0.f));
            const float e1 = __expf(fminf(p[1][r] - mnew, 0.f));
            const float e2 = __expf(fminf(p[2][r] - mnew, 0.f));
            const float e3 = __expf(fminf(p[3][r] - mnew, 0.f));
            float lsum = (e0 + e1) + (e2 + e3);
#pragma unroll
            for (int off = 1; off < 16; off <<= 1)
                lsum += __shfl_xor(lsum, off, 16);
            lrow[r] = lrow[r] * alpha[r] + lsum;
            mrow[r] = mnew;
            const int row = quad * 4 + r;
            Ps[wid][row][m]      = (__bf16)e0;
            Ps[wid][row][16 + m] = (__bf16)e1;
            Ps[wid][row][32 + m] = (__bf16)e2;
            Ps[wid][row][48 + m] = (__bf16)e3;
        }
#pragma unroll
        for (int c = 0; c < 4; c++)
#pragma unroll
            for (int r = 0; r < 4; r++) oacc[c][r] *= alpha[r];

        __syncthreads();   // Ps write->read order; Ks/Vt reads done pre-restage

        // ---- P.V : P A-frags from LDS, V^T B-frags from registers ----
        const bf16x8 pfA = load8(&Ps[wid][m][quad * 8]);
        const bf16x8 pfB = load8(&Ps[wid][m][32 + quad * 8]);
#pragma unroll
        for (int c = 0; c < 4; c++) {
            oacc[c] = MFMA16(pfA, vfA[c], oacc[c]);
            oacc[c] = MFMA16(pfB, vfB[c], oacc[c]);
        }
    }

    // ---- epilogue: O /= l, store concat [b, s, h*64+d] ----
#pragma unroll
    for (int r = 0; r < 4; r++) {
        const int s = q0 + quad * 4 + r;
        const float inv = 1.f / lrow[r];
#pragma unroll
        for (int c = 0; c < 4; c++) {
            const size_t o = ((size_t)(b * SEQ + s)) * D_MODEL + h * D_K + c * 16 + m;
            Cc[o] = (__bf16)(oacc[c][r] * inv);
        }
    }
}

// ---------------------------------------------------------------------------
// Output projection: Out = Cc * Wo^T + bo (fp32 out). Same m97 structure.
// grid = (32, 8), block = 256.
// ---------------------------------------------------------------------------
__global__ __launch_bounds__(256) void oproj_kernel(
    const __bf16* __restrict__ Cc,
    const float* __restrict__ Wo,
    const float* __restrict__ bo,
    float* __restrict__ Out)
{
    __shared__ __bf16 As[128 * 32];
    __shared__ float  Bsf[128 * 32];

    const int lane = threadIdx.x & 63;
    const int wid  = threadIdx.x >> 6;
    const int m    = lane & 15;
    const int quad = lane >> 4;
    const int wrow = wid >> 1, wcol = wid & 1;
    const int row0 = blockIdx.x * 128;
    const int col0 = blockIdx.y * 128;

    f32x4 acc[4][4];
#pragma unroll
    for (int i = 0; i < 4; i++)
#pragma unroll
        for (int j = 0; j < 4; j++) acc[i][j] = (f32x4){0.f, 0.f, 0.f, 0.f};

    for (int k0 = 0; k0 < D_MODEL; k0 += 32) {
#pragma unroll
        for (int i = 0; i < 2; i++) {
            const int slot = wid * 128 + i * 64 + lane;
            const int arow = slot >> 2, k8 = slot & 3;
            gload16(Cc + (size_t)(row0 + arow) * D_MODEL + k0 + k8 * 8,
                    (const char*)As + (size_t)(wid * 128 + i * 64) * 16);
        }
#pragma unroll
        for (int i = 0; i < 4; i++) {
            const int slot = wid * 256 + i * 64 + lane;
            const int brow = slot >> 3, k4s = slot & 7;
            const int k4g = k4s ^ (brow & 7);
            gload16(Wo + (size_t)(col0 + brow) * D_MODEL + k0 + k4g * 4,
                    (const char*)Bsf + (size_t)(wid * 256 + i * 64) * 16);
        }
        __syncthreads();

        bf16x8 a[4], b[4];
#pragma unroll
        for (int i = 0; i < 4; i++)
            a[i] = load8(&As[(wrow * 64 + i * 16 + m) * 32 + quad * 8]);
#pragma unroll
        for (int j = 0; j < 4; j++) {
            const int brow = wcol * 64 + j * 16 + m;
            const int sw = brow & 7;
            const f32x4 lof = *reinterpret_cast<const f32x4*>(
                &Bsf[brow * 32 + (((quad * 2 + 0) ^ sw) * 4)]);
            const f32x4 hif = *reinterpret_cast<const f32x4*>(
                &Bsf[brow * 32 + (((quad * 2 + 1) ^ sw) * 4)]);
#pragma unroll
            for (int e = 0; e < 4; e++) { b[j][e] = (__bf16)lof[e]; b[j][4 + e] = (__bf16)hif[e]; }
        }
#pragma unroll
        for (int i = 0; i < 4; i++)
#pragma unroll
            for (int j = 0; j < 4; j++)
                acc[i][j] = MFMA16(a[i], b[j], acc[i][j]);
        __syncthreads();
    }

#pragma unroll
    for (int i = 0; i < 4; i++) {
#pragma unroll
        for (int r = 0; r < 4; r++) {
            const int R = row0 + wrow * 64 + i * 16 + quad * 4 + r;
#pragma unroll
            for (int j = 0; j < 4; j++) {
                const int E = col0 + wcol * 64 + j * 16 + m;
                Out[(size_t)R * D_MODEL + E] = acc[i][j][r] + bo[E];
            }
        }
    }
}

// ---------------------------------------------------------------------------
extern "C" void kernel_launch(void* const* d_in, const int* in_sizes, int n_in,
                              void* d_out, int out_size, void* d_ws, size_t ws_size,
                              hipStream_t stream) {
    const float* x  = (const float*)d_in[0];
    const float* Wq = (const float*)d_in[1];
    const float* Wk = (const float*)d_in[2];
    const float* Wv = (const float*)d_in[3];
    const float* Wo = (const float*)d_in[4];
    const float* bo = (const float*)d_in[5];
    // d_in[6] = causal mask — recomputed from indices, not read.

    // ws (32 MB total): seg0 = xb during qkv, then Cc (x dead after qkv).
    const size_t elems = (size_t)M_TOTAL * D_MODEL;   // 4194304
    __bf16* xb  = (__bf16*)d_ws;       // seg0: x (bf16) -> later Cc
    __bf16* Qb  = xb + elems;          // [32][2048][64]
    __bf16* Kb  = Qb + elems;          // [32][2048][64]
    __bf16* Vtg = Kb + elems;          // [32][64][2048]  (V^T)
    __bf16* Cc  = xb;                  // concat buffer aliases xb

    // 0) x fp32 -> bf16
    convert_kernel<<<dim3((int)(elems / 8 / 256)), 256, 0, stream>>>(x, xb);

    // 1) QKV projections (m97-style GEMM, fused via grid.y across 3 weights)
    qkv_kernel<<<dim3(M_TOTAL / 128, 3 * D_MODEL / 128), 256, 0, stream>>>(
        xb, Wq, Wk, Wv, Qb, Kb, Vtg);

    // 2) causal flash attention (balanced qx permutation) -> concat bf16
    attn_kernel<<<dim3(BATCH * NUM_HEADS, SEQ / 64), 256, 0, stream>>>(
        Qb, Kb, Vtg, Cc);

    // 3) output projection + bias -> fp32 out
    oproj_kernel<<<dim3(M_TOTAL / 128, D_MODEL / 128), 256, 0, stream>>>(
        Cc, Wo, bo, (float*)d_out);
}

// Round 5
// 219.009 us; speedup vs baseline: 2.4985x; 1.1597x over previous
//
#include <hip/hip_runtime.h>
#include <hip/hip_bf16.h>
#include <stdint.h>

typedef __bf16 bf16x8 __attribute__((ext_vector_type(8)));
typedef __bf16 bf16x4 __attribute__((ext_vector_type(4)));
typedef float  f32x4  __attribute__((ext_vector_type(4)));

#define D_MODEL 1024
#define NUM_HEADS 16
#define D_K 64
#define BATCH 2
#define SEQ 2048
#define M_TOTAL (BATCH * SEQ)   // 4096

static __device__ __forceinline__ bf16x8 load8(const __bf16* p) {
    return *reinterpret_cast<const bf16x8*>(p);
}

#define MFMA16(a, b, c) __builtin_amdgcn_mfma_f32_16x16x32_bf16((a), (b), (c), 0, 0, 0)

// Async global->LDS, 16B per lane. LDS dest = wave-uniform base + lane*16.
static __device__ __forceinline__ void gload16(const void* g, const void* lds) {
    __builtin_amdgcn_global_load_lds(
        (const __attribute__((address_space(1))) uint32_t*)g,
        (__attribute__((address_space(3))) uint32_t*)lds,
        16, 0, 0);
}

// ---------------------------------------------------------------------------
// fp32 -> bf16, 8 elems/thread. grid.x * 2048 elems total.
// ---------------------------------------------------------------------------
__global__ __launch_bounds__(256) void convert_kernel(
    const float* __restrict__ X, __bf16* __restrict__ Xb)
{
    const int idx = blockIdx.x * 256 + threadIdx.x;
    const f32x4 a = *reinterpret_cast<const f32x4*>(X + (size_t)idx * 8);
    const f32x4 b = *reinterpret_cast<const f32x4*>(X + (size_t)idx * 8 + 4);
    bf16x8 r;
#pragma unroll
    for (int e = 0; e < 4; e++) { r[e] = (__bf16)a[e]; r[4 + e] = (__bf16)b[e]; }
    *reinterpret_cast<bf16x8*>(Xb + (size_t)idx * 8) = r;
}

// All four weight matrices (1M elems each), grid = (512, 4).
__global__ __launch_bounds__(256) void convertw_kernel(
    const float* __restrict__ Wq, const float* __restrict__ Wk,
    const float* __restrict__ Wv, const float* __restrict__ Wo,
    __bf16* __restrict__ dq, __bf16* __restrict__ dk,
    __bf16* __restrict__ dv, __bf16* __restrict__ dw)
{
    const float* src = (blockIdx.y == 0) ? Wq : (blockIdx.y == 1) ? Wk
                     : (blockIdx.y == 2) ? Wv : Wo;
    __bf16* dst      = (blockIdx.y == 0) ? dq : (blockIdx.y == 1) ? dk
                     : (blockIdx.y == 2) ? dv : dw;
    const int idx = blockIdx.x * 256 + threadIdx.x;
    const f32x4 a = *reinterpret_cast<const f32x4*>(src + (size_t)idx * 8);
    const f32x4 b = *reinterpret_cast<const f32x4*>(src + (size_t)idx * 8 + 4);
    bf16x8 r;
#pragma unroll
    for (int e = 0; e < 4; e++) { r[e] = (__bf16)a[e]; r[4 + e] = (__bf16)b[e]; }
    *reinterpret_cast<bf16x8*>(dst + (size_t)idx * 8) = r;
}

// ---------------------------------------------------------------------------
// Shared epilogue for the QKV GEMM: remap C tile to per-head layouts.
// ---------------------------------------------------------------------------
static __device__ __forceinline__ void qkv_epilogue(
    const f32x4 (&acc)[4][4], int row0, int lcol0, int wsel,
    int wrow, int wcol, int m, int quad,
    __bf16* __restrict__ Qb, __bf16* __restrict__ Kb, __bf16* __restrict__ Vtg)
{
#pragma unroll
    for (int i = 0; i < 4; i++) {
#pragma unroll
        for (int r = 0; r < 4; r++) {
            const int R  = row0 + wrow * 64 + i * 16 + quad * 4 + r;
            const int bb = R >> 11;
            const int s  = R & (SEQ - 1);
#pragma unroll
            for (int j = 0; j < 4; j++) {
                const int e  = lcol0 + wcol * 64 + j * 16 + m;
                const int h  = e >> 6;
                const int dk = e & (D_K - 1);
                const int bh = bb * NUM_HEADS + h;
                const __bf16 v = (__bf16)acc[i][j][r];
                if (wsel == 2)
                    Vtg[((size_t)bh * D_K + dk) * SEQ + s] = v;            // V^T
                else if (wsel == 1)
                    Kb[((size_t)bh * SEQ + s) * D_K + dk] = v;
                else
                    Qb[((size_t)bh * SEQ + s) * D_K + dk] = v;
            }
        }
    }
}

// ---------------------------------------------------------------------------
// QKV GEMM, all-bf16 (path A): 128x128 tile, BK=32, gload16 for A and B.
// grid = (32, 24), block = 256.
// ---------------------------------------------------------------------------
__global__ __launch_bounds__(256) void qkv_kernel_b(
    const __bf16* __restrict__ Xb,
    const __bf16* __restrict__ Wqb,
    const __bf16* __restrict__ Wkb,
    const __bf16* __restrict__ Wvb,
    __bf16* __restrict__ Qb,
    __bf16* __restrict__ Kb,
    __bf16* __restrict__ Vtg)
{
    __shared__ __bf16 As[128 * 32];
    __shared__ __bf16 Bs[128 * 32];

    const int lane = threadIdx.x & 63;
    const int wid  = threadIdx.x >> 6;
    const int m    = lane & 15;
    const int quad = lane >> 4;
    const int wrow = wid >> 1, wcol = wid & 1;
    const int row0 = blockIdx.x * 128;
    const int col0 = blockIdx.y * 128;
    const int wsel = col0 >> 10;
    const int lcol0 = col0 & 1023;

    const __bf16* W = (wsel == 0) ? Wqb : (wsel == 1) ? Wkb : Wvb;

    f32x4 acc[4][4];
#pragma unroll
    for (int i = 0; i < 4; i++)
#pragma unroll
        for (int j = 0; j < 4; j++) acc[i][j] = (f32x4){0.f, 0.f, 0.f, 0.f};

    for (int k0 = 0; k0 < D_MODEL; k0 += 32) {
#pragma unroll
        for (int i = 0; i < 2; i++) {
            const int slot = wid * 128 + i * 64 + lane;
            const int arow = slot >> 2, k8 = slot & 3;
            gload16(Xb + (size_t)(row0 + arow) * D_MODEL + k0 + k8 * 8,
                    (const char*)As + (size_t)(wid * 128 + i * 64) * 16);
            gload16(W + (size_t)(lcol0 + arow) * D_MODEL + k0 + k8 * 8,
                    (const char*)Bs + (size_t)(wid * 128 + i * 64) * 16);
        }
        __syncthreads();

        bf16x8 a[4], b[4];
#pragma unroll
        for (int i = 0; i < 4; i++)
            a[i] = load8(&As[(wrow * 64 + i * 16 + m) * 32 + quad * 8]);
#pragma unroll
        for (int j = 0; j < 4; j++)
            b[j] = load8(&Bs[(wcol * 64 + j * 16 + m) * 32 + quad * 8]);
#pragma unroll
        for (int i = 0; i < 4; i++)
#pragma unroll
            for (int j = 0; j < 4; j++)
                acc[i][j] = MFMA16(a[i], b[j], acc[i][j]);
        __syncthreads();
    }
    qkv_epilogue(acc, row0, lcol0, wsel, wrow, wcol, m, quad, Qb, Kb, Vtg);
}

// ---------------------------------------------------------------------------
// QKV GEMM, fp32-B fallback (path B) — round-4 kernel, unchanged.
// ---------------------------------------------------------------------------
__global__ __launch_bounds__(256) void qkv_kernel(
    const __bf16* __restrict__ Xb,
    const float* __restrict__ Wq,
    const float* __restrict__ Wk,
    const float* __restrict__ Wv,
    __bf16* __restrict__ Qb,
    __bf16* __restrict__ Kb,
    __bf16* __restrict__ Vtg)
{
    __shared__ __bf16 As[128 * 32];
    __shared__ float  Bsf[128 * 32];

    const int lane = threadIdx.x & 63;
    const int wid  = threadIdx.x >> 6;
    const int m    = lane & 15;
    const int quad = lane >> 4;
    const int wrow = wid >> 1, wcol = wid & 1;
    const int row0 = blockIdx.x * 128;
    const int col0 = blockIdx.y * 128;
    const int wsel = col0 >> 10;
    const int lcol0 = col0 & 1023;

    const float* W = (wsel == 0) ? Wq : (wsel == 1) ? Wk : Wv;

    f32x4 acc[4][4];
#pragma unroll
    for (int i = 0; i < 4; i++)
#pragma unroll
        for (int j = 0; j < 4; j++) acc[i][j] = (f32x4){0.f, 0.f, 0.f, 0.f};

    for (int k0 = 0; k0 < D_MODEL; k0 += 32) {
#pragma unroll
        for (int i = 0; i < 2; i++) {
            const int slot = wid * 128 + i * 64 + lane;
            const int arow = slot >> 2, k8 = slot & 3;
            gload16(Xb + (size_t)(row0 + arow) * D_MODEL + k0 + k8 * 8,
                    (const char*)As + (size_t)(wid * 128 + i * 64) * 16);
        }
#pragma unroll
        for (int i = 0; i < 4; i++) {
            const int slot = wid * 256 + i * 64 + lane;
            const int brow = slot >> 3, k4s = slot & 7;
            const int k4g = k4s ^ (brow & 7);
            gload16(W + (size_t)(lcol0 + brow) * D_MODEL + k0 + k4g * 4,
                    (const char*)Bsf + (size_t)(wid * 256 + i * 64) * 16);
        }
        __syncthreads();

        bf16x8 a[4], b[4];
#pragma unroll
        for (int i = 0; i < 4; i++)
            a[i] = load8(&As[(wrow * 64 + i * 16 + m) * 32 + quad * 8]);
#pragma unroll
        for (int j = 0; j < 4; j++) {
            const int brow = wcol * 64 + j * 16 + m;
            const int sw = brow & 7;
            const f32x4 lo = *reinterpret_cast<const f32x4*>(
                &Bsf[brow * 32 + (((quad * 2 + 0) ^ sw) * 4)]);
            const f32x4 hi = *reinterpret_cast<const f32x4*>(
                &Bsf[brow * 32 + (((quad * 2 + 1) ^ sw) * 4)]);
#pragma unroll
            for (int e = 0; e < 4; e++) { b[j][e] = (__bf16)lo[e]; b[j][4 + e] = (__bf16)hi[e]; }
        }
#pragma unroll
        for (int i = 0; i < 4; i++)
#pragma unroll
            for (int j = 0; j < 4; j++)
                acc[i][j] = MFMA16(a[i], b[j], acc[i][j]);
        __syncthreads();
    }
    qkv_epilogue(acc, row0, lcol0, wsel, wrow, wcol, m, quad, Qb, Kb, Vtg);
}

// ---------------------------------------------------------------------------
// Flash attention, causal, Br=128, Bc=64, S^T layout.
// grid = (32 bh, 16 qy), block = 256 (4 waves; wave owns 32 q rows).
//
// S^T trick: compute S^T = K·Q^T (A=K-frags from LDS, B=Q-frags in regs).
// C-layout: col = q (lane m), row = key (quad*4+r) -> each thread holds 16
// scores (4 kb x 4 r) for ONE q per group: key-reduction = in-thread tree +
// 2 shuffles (xor 16/32) instead of round-4's 4-step m-lane butterflies
// (32 bpermutes/tile -> 4). m/l/alpha are scalar per (thread, qg); alpha and
// 1/l are broadcast to the O C-layout (row=q) via a tiny LDS array Alf.
// Balanced qx map: co-resident pairs {lo, 15-lo} sum to 34 tiles.
// ---------------------------------------------------------------------------
__global__ __launch_bounds__(256) void attn_kernel(
    const __bf16* __restrict__ Qb,
    const __bf16* __restrict__ Kb,
    const __bf16* __restrict__ Vtg,
    __bf16* __restrict__ Cc)
{
    __shared__ alignas(16) __bf16 Ks[64][72];      // [key][d], +8 pad
    __shared__ alignas(16) __bf16 Vt[64][72];      // [d][key], +8 pad
    __shared__ alignas(16) __bf16 Pw[4][32][72];   // per-wave P[q_local][key]
    __shared__ alignas(16) float  Alf[4][2][16];   // per-wave alpha / 1-over-l

    const int lane = threadIdx.x & 63;
    const int wid  = threadIdx.x >> 6;
    const int m    = lane & 15;
    const int quad = lane >> 4;
    const int bh   = blockIdx.x;
    const int b    = bh >> 4;
    const int h    = bh & (NUM_HEADS - 1);

    const int lo = blockIdx.y & 7, hi = blockIdx.y >> 3;
    const int qx = hi ? (15 - lo) : lo;

    const __bf16* Qp = Qb  + (size_t)bh * SEQ * D_K;
    const __bf16* Kp = Kb  + (size_t)bh * SEQ * D_K;
    const __bf16* Vp = Vtg + (size_t)bh * D_K * SEQ;

    const int q0w = qx * 128 + wid * 32;   // this wave's first q row

    // Q as B-fragments (col n = q = m, k-dim = d), kept in registers.
    bf16x8 qB[2][2];
#pragma unroll
    for (int qg = 0; qg < 2; qg++)
#pragma unroll
        for (int ch = 0; ch < 2; ch++)
            qB[qg][ch] = load8(Qp + (size_t)(q0w + qg * 16 + m) * D_K + ch * 32 + quad * 8);

    f32x4 oacc[2][4];
#pragma unroll
    for (int qg = 0; qg < 2; qg++)
#pragma unroll
        for (int c = 0; c < 4; c++) oacc[qg][c] = (f32x4){0.f, 0.f, 0.f, 0.f};
    float mrow[2] = {-1e30f, -1e30f};
    float lrow[2] = {0.f, 0.f};

    const int ntiles = 2 * qx + 2;
    for (int t = 0; t < ntiles; t++) {
        const int k0 = t * 64;
        // ---- cooperative vector staging: K[64][64], V^T[64][64] ----
        {
            const int a = threadIdx.x >> 2;          // 0..63
            const int c = (threadIdx.x & 3) * 16;    // 0,16,32,48
            *reinterpret_cast<bf16x8*>(&Ks[a][c])     = load8(Kp + (size_t)(k0 + a) * D_K + c);
            *reinterpret_cast<bf16x8*>(&Ks[a][c + 8]) = load8(Kp + (size_t)(k0 + a) * D_K + c + 8);
            *reinterpret_cast<bf16x8*>(&Vt[a][c])     = load8(Vp + (size_t)a * SEQ + k0 + c);
            *reinterpret_cast<bf16x8*>(&Vt[a][c + 8]) = load8(Vp + (size_t)a * SEQ + k0 + c + 8);
        }
        __syncthreads();

        // ---- S^T = K Q^T: rows = keys, cols = q; mask + scale ----
        float p[2][4][4];   // [qg][kb][r]
#pragma unroll
        for (int kb = 0; kb < 4; kb++) {
            const bf16x8 kfA = load8(&Ks[kb * 16 + m][quad * 8]);
            const bf16x8 kfB = load8(&Ks[kb * 16 + m][32 + quad * 8]);
#pragma unroll
            for (int qg = 0; qg < 2; qg++) {
                f32x4 st = (f32x4){0.f, 0.f, 0.f, 0.f};
                st = MFMA16(kfA, qB[qg][0], st);
                st = MFMA16(kfB, qB[qg][1], st);
                const int q = q0w + qg * 16 + m;
#pragma unroll
                for (int r = 0; r < 4; r++) {
                    const int key = k0 + kb * 16 + quad * 4 + r;
                    p[qg][kb][r] = (key <= q) ? st[r] * 0.125f : -1e30f;
                }
            }
        }

        // ---- V fragments (Vt restaged next tile; read before sync2) ----
        bf16x8 vfA[4], vfB[4];
#pragma unroll
        for (int c = 0; c < 4; c++) {
            vfA[c] = load8(&Vt[c * 16 + m][quad * 8]);
            vfB[c] = load8(&Vt[c * 16 + m][32 + quad * 8]);
        }

        // ---- online softmax: in-thread tree + 2 shuffles per qg ----
#pragma unroll
        for (int qg = 0; qg < 2; qg++) {
            float vmax = -1e30f;
#pragma unroll
            for (int kb = 0; kb < 4; kb++)
#pragma unroll
                for (int r = 0; r < 4; r++) vmax = fmaxf(vmax, p[qg][kb][r]);
            vmax = fmaxf(vmax, __shfl_xor(vmax, 16));
            vmax = fmaxf(vmax, __shfl_xor(vmax, 32));
            const float mnew  = fmaxf(mrow[qg], vmax);
            const float alpha = __expf(fminf(mrow[qg] - mnew, 0.f));
            float lsum = 0.f;
#pragma unroll
            for (int kb = 0; kb < 4; kb++) {
                bf16x4 pk;
#pragma unroll
                for (int r = 0; r < 4; r++) {
                    const float e = __expf(fminf(p[qg][kb][r] - mnew, 0.f));
                    lsum += e;
                    pk[r] = (__bf16)e;
                }
                *reinterpret_cast<bf16x4*>(&Pw[wid][qg * 16 + m][kb * 16 + quad * 4]) = pk;
            }
            lsum += __shfl_xor(lsum, 16);
            lsum += __shfl_xor(lsum, 32);
            lrow[qg] = lrow[qg] * alpha + lsum;
            mrow[qg] = mnew;
            if (quad == 0) Alf[wid][qg][m] = alpha;   // uniform across quads
        }

        __syncthreads();   // Pw/Alf visible; Ks/Vt reads done before restage

        // ---- rescale O by alpha (broadcast via Alf) + P·V ----
#pragma unroll
        for (int qg = 0; qg < 2; qg++) {
            const f32x4 af = *reinterpret_cast<const f32x4*>(&Alf[wid][qg][quad * 4]);
#pragma unroll
            for (int c = 0; c < 4; c++)
#pragma unroll
                for (int r = 0; r < 4; r++) oacc[qg][c][r] *= af[r];
            const bf16x8 pfA = load8(&Pw[wid][qg * 16 + m][quad * 8]);
            const bf16x8 pfB = load8(&Pw[wid][qg * 16 + m][32 + quad * 8]);
#pragma unroll
            for (int c = 0; c < 4; c++) {
                oacc[qg][c] = MFMA16(pfA, vfA[c], oacc[qg][c]);
                oacc[qg][c] = MFMA16(pfB, vfB[c], oacc[qg][c]);
            }
        }
    }

    // ---- epilogue: broadcast 1/l via Alf, store concat [b, s, h*64+d] ----
    __syncthreads();
    if (quad == 0) { Alf[wid][0][m] = lrow[0]; Alf[wid][1][m] = lrow[1]; }
    __syncthreads();
#pragma unroll
    for (int qg = 0; qg < 2; qg++) {
        const f32x4 lf = *reinterpret_cast<const f32x4*>(&Alf[wid][qg][quad * 4]);
#pragma unroll
        for (int r = 0; r < 4; r++) {
            const int s = q0w + qg * 16 + quad * 4 + r;
            const float inv = 1.f / lf[r];
#pragma unroll
            for (int c = 0; c < 4; c++) {
                const size_t o = ((size_t)(b * SEQ + s)) * D_MODEL + h * D_K + c * 16 + m;
                Cc[o] = (__bf16)(oacc[qg][c][r] * inv);
            }
        }
    }
}

// ---------------------------------------------------------------------------
// Output projection, all-bf16 B (path A). grid = (32, 8).
// ---------------------------------------------------------------------------
__global__ __launch_bounds__(256) void oproj_kernel_b(
    const __bf16* __restrict__ Cc,
    const __bf16* __restrict__ Wob,
    const float* __restrict__ bo,
    float* __restrict__ Out)
{
    __shared__ __bf16 As[128 * 32];
    __shared__ __bf16 Bs[128 * 32];

    const int lane = threadIdx.x & 63;
    const int wid  = threadIdx.x >> 6;
    const int m    = lane & 15;
    const int quad = lane >> 4;
    const int wrow = wid >> 1, wcol = wid & 1;
    const int row0 = blockIdx.x * 128;
    const int col0 = blockIdx.y * 128;

    f32x4 acc[4][4];
#pragma unroll
    for (int i = 0; i < 4; i++)
#pragma unroll
        for (int j = 0; j < 4; j++) acc[i][j] = (f32x4){0.f, 0.f, 0.f, 0.f};

    for (int k0 = 0; k0 < D_MODEL; k0 += 32) {
#pragma unroll
        for (int i = 0; i < 2; i++) {
            const int slot = wid * 128 + i * 64 + lane;
            const int arow = slot >> 2, k8 = slot & 3;
            gload16(Cc + (size_t)(row0 + arow) * D_MODEL + k0 + k8 * 8,
                    (const char*)As + (size_t)(wid * 128 + i * 64) * 16);
            gload16(Wob + (size_t)(col0 + arow) * D_MODEL + k0 + k8 * 8,
                    (const char*)Bs + (size_t)(wid * 128 + i * 64) * 16);
        }
        __syncthreads();

        bf16x8 a[4], b[4];
#pragma unroll
        for (int i = 0; i < 4; i++)
            a[i] = load8(&As[(wrow * 64 + i * 16 + m) * 32 + quad * 8]);
#pragma unroll
        for (int j = 0; j < 4; j++)
            b[j] = load8(&Bs[(wcol * 64 + j * 16 + m) * 32 + quad * 8]);
#pragma unroll
        for (int i = 0; i < 4; i++)
#pragma unroll
            for (int j = 0; j < 4; j++)
                acc[i][j] = MFMA16(a[i], b[j], acc[i][j]);
        __syncthreads();
    }

#pragma unroll
    for (int i = 0; i < 4; i++) {
#pragma unroll
        for (int r = 0; r < 4; r++) {
            const int R = row0 + wrow * 64 + i * 16 + quad * 4 + r;
#pragma unroll
            for (int j = 0; j < 4; j++) {
                const int E = col0 + wcol * 64 + j * 16 + m;
                Out[(size_t)R * D_MODEL + E] = acc[i][j][r] + bo[E];
            }
        }
    }
}

// ---------------------------------------------------------------------------
// Output projection, fp32-B fallback (path B) — round-4 kernel, unchanged.
// ---------------------------------------------------------------------------
__global__ __launch_bounds__(256) void oproj_kernel(
    const __bf16* __restrict__ Cc,
    const float* __restrict__ Wo,
    const float* __restrict__ bo,
    float* __restrict__ Out)
{
    __shared__ __bf16 As[128 * 32];
    __shared__ float  Bsf[128 * 32];

    const int lane = threadIdx.x & 63;
    const int wid  = threadIdx.x >> 6;
    const int m    = lane & 15;
    const int quad = lane >> 4;
    const int wrow = wid >> 1, wcol = wid & 1;
    const int row0 = blockIdx.x * 128;
    const int col0 = blockIdx.y * 128;

    f32x4 acc[4][4];
#pragma unroll
    for (int i = 0; i < 4; i++)
#pragma unroll
        for (int j = 0; j < 4; j++) acc[i][j] = (f32x4){0.f, 0.f, 0.f, 0.f};

    for (int k0 = 0; k0 < D_MODEL; k0 += 32) {
#pragma unroll
        for (int i = 0; i < 2; i++) {
            const int slot = wid * 128 + i * 64 + lane;
            const int arow = slot >> 2, k8 = slot & 3;
            gload16(Cc + (size_t)(row0 + arow) * D_MODEL + k0 + k8 * 8,
                    (const char*)As + (size_t)(wid * 128 + i * 64) * 16);
        }
#pragma unroll
        for (int i = 0; i < 4; i++) {
            const int slot = wid * 256 + i * 64 + lane;
            const int brow = slot >> 3, k4s = slot & 7;
            const int k4g = k4s ^ (brow & 7);
            gload16(Wo + (size_t)(col0 + brow) * D_MODEL + k0 + k4g * 4,
                    (const char*)Bsf + (size_t)(wid * 256 + i * 64) * 16);
        }
        __syncthreads();

        bf16x8 a[4], b[4];
#pragma unroll
        for (int i = 0; i < 4; i++)
            a[i] = load8(&As[(wrow * 64 + i * 16 + m) * 32 + quad * 8]);
#pragma unroll
        for (int j = 0; j < 4; j++) {
            const int brow = wcol * 64 + j * 16 + m;
            const int sw = brow & 7;
            const f32x4 lof = *reinterpret_cast<const f32x4*>(
                &Bsf[brow * 32 + (((quad * 2 + 0) ^ sw) * 4)]);
            const f32x4 hif = *reinterpret_cast<const f32x4*>(
                &Bsf[brow * 32 + (((quad * 2 + 1) ^ sw) * 4)]);
#pragma unroll
            for (int e = 0; e < 4; e++) { b[j][e] = (__bf16)lof[e]; b[j][4 + e] = (__bf16)hif[e]; }
        }
#pragma unroll
        for (int i = 0; i < 4; i++)
#pragma unroll
            for (int j = 0; j < 4; j++)
                acc[i][j] = MFMA16(a[i], b[j], acc[i][j]);
        __syncthreads();
    }

#pragma unroll
    for (int i = 0; i < 4; i++) {
#pragma unroll
        for (int r = 0; r < 4; r++) {
            const int R = row0 + wrow * 64 + i * 16 + quad * 4 + r;
#pragma unroll
            for (int j = 0; j < 4; j++) {
                const int E = col0 + wcol * 64 + j * 16 + m;
                Out[(size_t)R * D_MODEL + E] = acc[i][j][r] + bo[E];
            }
        }
    }
}

// ---------------------------------------------------------------------------
extern "C" void kernel_launch(void* const* d_in, const int* in_sizes, int n_in,
                              void* d_out, int out_size, void* d_ws, size_t ws_size,
                              hipStream_t stream) {
    const float* x  = (const float*)d_in[0];
    const float* Wq = (const float*)d_in[1];
    const float* Wk = (const float*)d_in[2];
    const float* Wv = (const float*)d_in[3];
    const float* Wo = (const float*)d_in[4];
    const float* bo = (const float*)d_in[5];
    // d_in[6] = causal mask — recomputed from indices, not read.

    const size_t elems  = (size_t)M_TOTAL * D_MODEL;   // 4194304
    const size_t welems = (size_t)D_MODEL * D_MODEL;   // 1048576
    __bf16* xb  = (__bf16*)d_ws;       // seg0: x (bf16) -> later Cc (aliased)
    __bf16* Qb  = xb + elems;          // [32][2048][64]
    __bf16* Kb  = Qb + elems;          // [32][2048][64]
    __bf16* Vtg = Kb + elems;          // [32][64][2048]  (V^T)
    __bf16* Cc  = xb;

    const size_t needA = (4 * elems + 4 * welems) * sizeof(__bf16);   // 40 MB

    // 0) x fp32 -> bf16
    convert_kernel<<<dim3((int)(elems / 2048)), 256, 0, stream>>>(x, xb);

    if (ws_size >= needA) {
        // Path A: pre-convert weights to bf16, pure-bf16 m97 GEMMs.
        __bf16* Wqb = Vtg + elems;
        __bf16* Wkb = Wqb + welems;
        __bf16* Wvb = Wkb + welems;
        __bf16* Wob = Wvb + welems;
        convertw_kernel<<<dim3((int)(welems / 2048), 4), 256, 0, stream>>>(
            Wq, Wk, Wv, Wo, Wqb, Wkb, Wvb, Wob);
        qkv_kernel_b<<<dim3(M_TOTAL / 128, 3 * D_MODEL / 128), 256, 0, stream>>>(
            xb, Wqb, Wkb, Wvb, Qb, Kb, Vtg);
        attn_kernel<<<dim3(BATCH * NUM_HEADS, SEQ / 128), 256, 0, stream>>>(
            Qb, Kb, Vtg, Cc);
        oproj_kernel_b<<<dim3(M_TOTAL / 128, D_MODEL / 128), 256, 0, stream>>>(
            Cc, Wob, bo, (float*)d_out);
    } else {
        // Path B: fp32-B staged GEMMs (round-4 structure).
        qkv_kernel<<<dim3(M_TOTAL / 128, 3 * D_MODEL / 128), 256, 0, stream>>>(
            xb, Wq, Wk, Wv, Qb, Kb, Vtg);
        attn_kernel<<<dim3(BATCH * NUM_HEADS, SEQ / 128), 256, 0, stream>>>(
            Qb, Kb, Vtg, Cc);
        oproj_kernel<<<dim3(M_TOTAL / 128, D_MODEL / 128), 256, 0, stream>>>(
            Cc, Wo, bo, (float*)d_out);
    }
}